// Round 5
// baseline (91.138 us; speedup 1.0000x reference)
//
#include <hip/hip_runtime.h>

#define NB   16
#define INF  512
#define OUTF 512
#define MAXR 256   // LDS row-list capacity per bank (c_b ~ 64 +/- 8)

typedef __attribute__((ext_vector_type(8))) short bf16x8;
typedef __attribute__((ext_vector_type(4))) float f32x4;

static __device__ __forceinline__ ushort f2bf(float f) {
    unsigned u = __float_as_uint(f);
    u += 0x7FFFu + ((u >> 16) & 1u);   // round-to-nearest-even
    return (ushort)(u >> 16);
}

static __device__ __forceinline__ bf16x8 cvt8(const float* __restrict__ p) {
    float4 v0 = *(const float4*)p;
    float4 v1 = *(const float4*)(p + 4);
    bf16x8 r;
    r[0] = (short)f2bf(v0.x); r[1] = (short)f2bf(v0.y);
    r[2] = (short)f2bf(v0.z); r[3] = (short)f2bf(v0.w);
    r[4] = (short)f2bf(v1.x); r[5] = (short)f2bf(v1.y);
    r[6] = (short)f2bf(v1.z); r[7] = (short)f2bf(v1.w);
    return r;
}

// ---------------- Single fused kernel ----------------
// grid = (32 o-tiles of 16 cols, 16 banks), 256 threads (4 waves).
// Phase 1: block scans sel[] and builds its bank's row list in LDS (order
//   within the bank is irrelevant -- each block covers ALL rows of its bank
//   for its disjoint 16-col out slice, so every (row,out) is written once).
// Phase 2: each wave converts its 16x512 W slab to bf16 ONCE into 64 VGPRs
//   (W touched exactly once from HBM, no staging buffer), then loops over
//   16-row tiles doing direct-to-fragment A loads + on-the-fly bf16 cvt +
//   mfma_f32_16x16x32_bf16. No ws, no second kernel, no barrier in K-loop.
__global__ __launch_bounds__(256) void fused_banked(
    const float* __restrict__ x, const int* __restrict__ sel,
    const float* __restrict__ W, const float* __restrict__ bias,
    float* __restrict__ out, int nrows)
{
    int bank = blockIdx.y;
    int o0 = blockIdx.x * 16;

    __shared__ int lst[MAXR];
    __shared__ int cnt_s;
    int t = threadIdx.x;
    if (t == 0) cnt_s = 0;
    __syncthreads();
    for (int r = t; r < nrows; r += 256) {
        if (sel[r] == bank) {
            int pos = atomicAdd(&cnt_s, 1);
            if (pos < MAXR) lst[pos] = r;
        }
    }
    __syncthreads();
    int c = cnt_s;
    if (c > MAXR) c = MAXR;
    int ntiles = (c + 15) >> 4;

    int lane = t & 63;
    int wave = t >> 6;
    int ln = lane & 15;   // A: row m | B: out col n | D: col n
    int q  = lane >> 4;   // k-quad: k offset = q*8

    // Convert this lane's W fragments once: W[bank][o0+ln][k+q*8 .. +8), all k.
    const float* wrow = W + ((size_t)bank * OUTF + o0 + ln) * INF + q * 8;
    bf16x8 bfr[16];
#pragma unroll
    for (int i = 0; i < 16; ++i) bfr[i] = cvt8(wrow + i * 32);

    float bv = bias[bank * OUTF + o0 + ln];

    for (int T = wave; T < ntiles; T += 4) {
        int row0 = T * 16;
        int rl = row0 + ln;
        int rg = lst[rl < c ? rl : 0];
        const float* ap = x + (size_t)rg * INF + q * 8;

        f32x4 acc = {0.f, 0.f, 0.f, 0.f};
#pragma unroll
        for (int i = 0; i < 16; ++i) {
            bf16x8 a = cvt8(ap + i * 32);
            acc = __builtin_amdgcn_mfma_f32_16x16x32_bf16(a, bfr[i], acc, 0, 0, 0);
        }

#pragma unroll
        for (int r = 0; r < 4; ++r) {
            int m = q * 4 + r;   // C/D: row = q*4 + reg, col = lane&15
            if (row0 + m < c)
                out[(size_t)lst[row0 + m] * OUTF + o0 + ln] = acc[r] + bv;
        }
    }
}

extern "C" void kernel_launch(void* const* d_in, const int* in_sizes, int n_in,
                              void* d_out, int out_size, void* d_ws, size_t ws_size,
                              hipStream_t stream) {
    const float* tensor = (const float*)d_in[0];   // (B,S,K,IN) fp32
    const int*   sel    = (const int*)d_in[1];     // (B,S,K) int32
    const float* weight = (const float*)d_in[2];   // (NB,OUT,IN) fp32
    const float* bias   = (const float*)d_in[3];   // (NB,OUT) fp32
    float* out = (float*)d_out;

    int nrows = in_sizes[1];                       // B*S*K = 1024

    dim3 grid(OUTF / 16, NB, 1);
    fused_banked<<<grid, 256, 0, stream>>>(tensor, sel, weight, bias, out, nrows);
}